// Round 4
// baseline (524.037 us; speedup 1.0000x reference)
//
#include <hip/hip_runtime.h>
#include <hip/hip_bf16.h>
#include <stdint.h>

// E=16 experts, C=256, CAP=4 -> F=1024, B=8, L=1024
#define EE 16
#define CC 256
#define FF 1024
#define LL 1024
#define BB 8
#define TL 64             // L-tile per block (8 waves; 2 independent blocks/CU)
#define FC 32             // f-chunk
#define NCH 32            // FF/FC
#define HSTR 40           // h row stride (bf16): 80 B, 16B-aligned for b128

typedef __bf16 bf16x8 __attribute__((ext_vector_type(8)));
typedef __bf16 bf16x4 __attribute__((ext_vector_type(4)));
typedef float  f32x4  __attribute__((ext_vector_type(4)));

__device__ __forceinline__ f32x4 mfma16(bf16x8 a, bf16x8 b, f32x4 c) {
    return __builtin_amdgcn_mfma_f32_16x16x32_bf16(a, b, c, 0, 0, 0);
}

// ---- merged weight pre-permute (fp32 -> bf16, granule-transposed) ----
// Coalesced read -> LDS transpose (padded) -> coalesced write.  [proven R1]
__global__ __launch_bounds__(256)
void cvt_both(const float* __restrict__ W1, const float* __restrict__ W2,
              __bf16* __restrict__ ws1, __bf16* __restrict__ ws2)
{
    __shared__ __align__(16) __bf16 ls[8448];
    const int t = threadIdx.x;
    const int bid = blockIdx.x;
    if (bid < 512) {
        const float* src = W1 + (size_t)bid * 8192;   // 32 f-rows x 256 c, contiguous
        #pragma unroll
        for (int i = 0; i < 8; ++i) {
            const int p = t + 256 * i;                // float4 index
            const float4 v = *(const float4*)(src + 4 * p);
            const int f = p >> 6, c4 = p & 63;
            const int cg = c4 >> 1, j0 = (c4 & 1) * 4;
            bf16x4 o;
            o[0] = (__bf16)v.x; o[1] = (__bf16)v.y; o[2] = (__bf16)v.z; o[3] = (__bf16)v.w;
            *(bf16x4*)(ls + cg * 264 + f * 8 + j0) = o;
        }
        __syncthreads();
        __bf16* dst = ws1 + (size_t)bid * 8192;
        #pragma unroll
        for (int i = 0; i < 4; ++i) {
            const int G = t + 256 * i;                // local granule = cg*32+f
            const int cg = G >> 5, f = G & 31;
            *(bf16x8*)(dst + (size_t)G * 8) = *(const bf16x8*)(ls + cg * 264 + f * 8);
        }
    } else {
        const int tile = bid - 512;
        const float* src = W2 + (size_t)(tile >> 5) * 262144 + (tile & 31) * 32;
        #pragma unroll
        for (int i = 0; i < 8; ++i) {
            const int u = t + 256 * i;
            const int c = u >> 3, col4 = u & 7;
            const float4 v = *(const float4*)(src + (size_t)c * 1024 + col4 * 4);
            const int fg = col4 >> 1, j0 = (col4 & 1) * 4;
            bf16x4 o;
            o[0] = (__bf16)v.x; o[1] = (__bf16)v.y; o[2] = (__bf16)v.z; o[3] = (__bf16)v.w;
            *(bf16x4*)(ls + fg * 2056 + c * 8 + j0) = o;
        }
        __syncthreads();
        __bf16* dst = ws2 + (size_t)tile * 8192;
        #pragma unroll
        for (int i = 0; i < 4; ++i) {
            const int G = t + 256 * i;                // local granule = fg*256+c
            const int fg = G >> 8, c = G & 255;
            *(bf16x8*)(dst + (size_t)G * 8) = *(const bf16x8*)(ls + fg * 2056 + c * 8);
        }
    }
}

// Fused expert MLP. Block = (b, e, 64-l tile), 8 waves, producer/consumer split.
// NO weight LDS staging: A-fragments read directly from global (L2-resident:
// 2 experts/XCD = 2 MB bf16 in a 4 MB L2).  LDS holds only the h handoff
// buffer (10 KB) -> 2 independent blocks/CU at <=128 VGPR.
// Waves 0-3 (producers): GEMM1(ch) -> silu -> sH[ch&1].  Hold x frags (64 VGPR).
// Waves 4-7 (consumers): GEMM2(ch-1) from sH[(ch-1)&1].  Hold y accum (64 VGPR).
// One barrier per chunk, protecting ONLY sH (the R1-proven handoff pattern).
__global__ __launch_bounds__(512, 4)
void experts_kernel(const float* __restrict__ x,
                    const __bf16* __restrict__ w1ws,
                    const float* __restrict__ b1,
                    const __bf16* __restrict__ w2ws,
                    const float* __restrict__ b2,
                    float* __restrict__ out)
{
    __shared__ __align__(16) __bf16 sH[2][2][32 * HSTR];  // 10 KB, [par][lw][row l][col f]

    const int tid  = threadIdx.x;
    const int lane = tid & 63;
    const int w    = tid >> 6;          // 0..7
    const int l15  = lane & 15, q4 = lane >> 4;
    const bool prod = (w < 4);
    const int wr   = w & 3;
    const int fh   = wr & 1;            // producer: f-half of chunk; consumer: c-half
    const int lw   = wr >> 1;           // 0..1: which 32-l range

    const int bid  = blockIdx.x;
    const int e    = ((bid & 7) << 1) | ((bid >> 3) & 1);  // 2 experts per XCD (L2 residency)
    const int rest = bid >> 4;          // 0..127
    const int bb   = rest & 7;
    const int l0   = (rest >> 3) * TL;  // 16 l-tiles
    const int lb   = l0 + 32 * lw;

    // per-lane weight base pointers (pre-permuted granule layout):
    // W1 frag (chunk ch, ks): elem (4ks+q4)*256 + (16fh+l15)*8 + ch*8192
    // W2 frag (chunk ch, u):  elem q4*2048 + (128fh+l15)*8 + u*128 + ch*8192
    const __bf16* w1p = w1ws + (size_t)e * (NCH * FC * CC)
                      + q4 * 256 + (16 * fh + l15) * 8;
    const __bf16* w2p = w2ws + (size_t)e * (NCH * CC * FC)
                      + q4 * 2048 + (128 * fh + l15) * 8;

    // Shared 64-VGPR pool: producers = x fragments (bf16x8 via bit_cast),
    // consumers = y accumulators (f32x4). Overlay keeps thread regs <= 128.
    f32x4 st[2][8];
    if (prod) {
        // x frags: B-layout, n=l15 (+16*lt), k(c) = 32*ks + 8*q4 + u
        const float* xp = x + ((size_t)(bb * EE + e) * CC) * LL + lb + l15;
        #pragma unroll
        for (int lt = 0; lt < 2; ++lt) {
            #pragma unroll
            for (int ks = 0; ks < 8; ++ks) {
                bf16x8 f;
                #pragma unroll
                for (int u = 0; u < 8; ++u)
                    f[u] = (__bf16)xp[(size_t)(32 * ks + 8 * q4 + u) * LL + 16 * lt];
                st[lt][ks] = __builtin_bit_cast(f32x4, f);
            }
        }
    } else {
        #pragma unroll
        for (int lt = 0; lt < 2; ++lt)
            #pragma unroll
            for (int u = 0; u < 8; ++u) st[lt][u] = f32x4{0.f, 0.f, 0.f, 0.f};
    }

    #pragma unroll 1
    for (int ch = 0; ch <= NCH; ++ch) {
        if (prod) {
            if (ch < NCH) {
                // ---- GEMM1: h[f-half, my 32 l] over K=C=256, A from global(L2) ----
                const float4 bv = *(const float4*)(b1 + e * FF + ch * FC + 16 * fh + 4 * q4);
                const __bf16* wp = w1p + (size_t)ch * 8192;
                f32x4 a0 = f32x4{0.f,0.f,0.f,0.f};
                f32x4 a1 = f32x4{0.f,0.f,0.f,0.f};
                #pragma unroll
                for (int ks = 0; ks < 8; ++ks) {
                    bf16x8 a = *(const bf16x8*)(wp + ks * 1024);
                    a0 = mfma16(a, __builtin_bit_cast(bf16x8, st[0][ks]), a0);
                    a1 = mfma16(a, __builtin_bit_cast(bf16x8, st[1][ks]), a1);
                }
                // bias + SiLU -> sH rows {l15, l15+16}, cols [16fh+4q4 .. +3]
                __bf16* hrow = &sH[ch & 1][lw][l15 * HSTR + 16 * fh + 4 * q4];
                bf16x4 hv;
                #pragma unroll
                for (int r = 0; r < 4; ++r) {
                    float v = a0[r] + ((const float*)&bv)[r];
                    hv[r] = (__bf16)(v / (1.0f + __expf(-v)));
                }
                *(bf16x4*)hrow = hv;
                #pragma unroll
                for (int r = 0; r < 4; ++r) {
                    float v = a1[r] + ((const float*)&bv)[r];
                    hv[r] = (__bf16)(v / (1.0f + __expf(-v)));
                }
                *(bf16x4*)(hrow + 16 * HSTR) = hv;
            }
        } else if (ch >= 1) {
            // ---- GEMM2: y[c-half, my 32 l] += W2[c, chunk ch-1] @ h(ch-1) ----
            const __bf16* hbase = &sH[(ch - 1) & 1][lw][l15 * HSTR + 8 * q4];
            bf16x8 h0 = *(const bf16x8*)(hbase);
            bf16x8 h1 = *(const bf16x8*)(hbase + 16 * HSTR);
            const __bf16* wp = w2p + (size_t)(ch - 1) * 8192;
            __builtin_amdgcn_s_setprio(1);
            #pragma unroll
            for (int u = 0; u < 8; ++u) {
                bf16x8 a = *(const bf16x8*)(wp + u * 128);
                st[0][u] = mfma16(a, h0, st[0][u]);
                st[1][u] = mfma16(a, h1, st[1][u]);
            }
            __builtin_amdgcn_s_setprio(0);
        }

        if (ch < NCH) __syncthreads();  // h(ch) handoff; also recycles sH[ch&1]
    }

    // ---- epilogue (consumers only): + b2, fp32 stores (16-lane 64B segments) ----
    if (!prod) {
        float* outp = out + ((size_t)(bb * EE + e) * CC) * LL + lb + l15;
        #pragma unroll
        for (int u = 0; u < 8; ++u) {
            const int c0 = 128 * fh + 16 * u + 4 * q4;
            const float4 b2v = *(const float4*)(b2 + e * CC + c0);
            #pragma unroll
            for (int lt = 0; lt < 2; ++lt) {
                #pragma unroll
                for (int r = 0; r < 4; ++r)
                    __builtin_nontemporal_store(
                        st[lt][u][r] + ((const float*)&b2v)[r],
                        outp + (size_t)(c0 + r) * LL + 16 * lt);
            }
        }
    }
}

extern "C" void kernel_launch(void* const* d_in, const int* in_sizes, int n_in,
                              void* d_out, int out_size, void* d_ws, size_t ws_size,
                              hipStream_t stream)
{
    const float* x  = (const float*)d_in[0];
    const float* W1 = (const float*)d_in[1];
    const float* b1 = (const float*)d_in[2];
    const float* W2 = (const float*)d_in[3];
    const float* b2 = (const float*)d_in[4];
    float* out = (float*)d_out;

    const size_t nW1 = (size_t)EE * FF * CC;   // 4194304 elems
    __bf16* w1bf = (__bf16*)d_ws;              // 8.39 MB
    __bf16* w2bf = w1bf + nW1;                 // + 8.39 MB

    cvt_both<<<dim3(1024), dim3(256), 0, stream>>>(W1, W2, w1bf, w2bf);

    experts_kernel<<<dim3(BB * EE * (LL / TL)), dim3(512), 0, stream>>>(
        x, w1bf, b1, w2bf, b2, out);
}